// Round 10
// baseline (385.249 us; speedup 1.0000x reference)
//
#include <hip/hip_runtime.h>

typedef __attribute__((ext_vector_type(8))) short bf16x8;
typedef __attribute__((ext_vector_type(4))) float f32x4;

__device__ __forceinline__ float b2f(unsigned short u) {
    union { unsigned int i; float f; } x; x.i = ((unsigned int)u) << 16; return x.f;
}
__device__ __forceinline__ unsigned short f2b(float f) {
    union { float f; unsigned int i; } x; x.f = f;
    unsigned int r = x.i + 0x7fffu + ((x.i >> 16) & 1u);  // RNE
    return (unsigned short)(r >> 16);
}

// async global->LDS, 16 B per lane (wave-uniform LDS base + lane*16 layout)
__device__ __forceinline__ void gl16(unsigned short* l, const unsigned short* g) {
    __builtin_amdgcn_global_load_lds((__attribute__((address_space(1))) void*)g,
                                     (__attribute__((address_space(3))) void*)l, 16, 0, 0);
}

// Partial Cox-de Boor exactly as the reference leaves it:
// cols 0-4 degree 3, col 5 degree 2, col 6 degree 1, col 7 degree 0.
// knots = [-1,-1,-1,-1,-0.6,-0.2,0.2,0.6,1,1,1,1]
__device__ __forceinline__ float kan_spline(float t, const float* cpf, float rwf) {
    float c3 = (t >= -1.0f && t < -0.6f) ? 1.0f : 0.0f;
    float c4 = (t >= -0.6f && t < -0.2f) ? 1.0f : 0.0f;
    float c5 = (t >= -0.2f && t <  0.2f) ? 1.0f : 0.0f;
    float c6 = (t >=  0.2f && t <  0.6f) ? 1.0f : 0.0f;
    float c7 = (t >=  0.6f && t <  1.0f) ? 1.0f : 0.0f;
    float d2 = (-0.6f - t) * 2.5f * c3;
    float d3 = (t + 1.0f) * 2.5f * c3 + (-0.2f - t) * 2.5f * c4;
    float d4 = (t + 0.6f) * 2.5f * c4 + ( 0.2f - t) * 2.5f * c5;
    float d5 = (t + 0.2f) * 2.5f * c5 + ( 0.6f - t) * 2.5f * c6;
    float d6 = (t - 0.2f) * 2.5f * c6 + ( 1.0f - t) * 2.5f * c7;
    float e1 = (-0.6f - t) * 2.5f  * d2;
    float e2 = (t + 1.0f) * 2.5f  * d2 + (-0.2f - t) * 1.25f * d3;
    float e3 = (t + 1.0f) * 1.25f * d3 + ( 0.2f - t) * 1.25f * d4;
    float e4 = (t + 0.6f) * 1.25f * d4 + ( 0.6f - t) * 1.25f * d5;
    float e5 = (t + 0.2f) * 1.25f * d5 + ( 1.0f - t) * 1.25f * d6;
    const float r12 = 1.0f / 1.2f;
    float f0 = (-0.6f - t) * 2.5f  * e1;
    float f1 = (t + 1.0f) * 2.5f  * e1 + (-0.2f - t) * 1.25f * e2;
    float f2 = (t + 1.0f) * 1.25f * e2 + ( 0.2f - t) * r12   * e3;
    float f3 = (t + 1.0f) * r12   * e3 + ( 0.6f - t) * r12   * e4;
    float f4 = (t + 0.6f) * r12   * e4 + ( 1.0f - t) * r12   * e5;
    float sp = f0*cpf[0] + f1*cpf[1] + f2*cpf[2] + f3*cpf[3] + f4*cpf[4]
             + e5*cpf[5] + d6*cpf[6] + c7*cpf[7];
    float v = sp * rwf;
    return fminf(fmaxf(v, -10.0f), 10.0f);
}

// per-row mean / rstd of x[1024,2048] f32, fp64 accumulate (fallback paths)
__global__ void ln_stats_kernel(const float* __restrict__ x,
                                float* __restrict__ mu, float* __restrict__ rstd) {
    const int row = blockIdx.x;
    const float* p = x + (size_t)row * 2048 + threadIdx.x * 8;
    double s = 0.0, q = 0.0;
#pragma unroll
    for (int i = 0; i < 8; ++i) { float v = p[i]; s += v; q += (double)v * v; }
    for (int o = 32; o > 0; o >>= 1) { s += __shfl_down(s, o, 64); q += __shfl_down(q, o, 64); }
    __shared__ double shs[4], shq[4];
    const int lane = threadIdx.x & 63, w = threadIdx.x >> 6;
    if (lane == 0) { shs[w] = s; shq[w] = q; }
    __syncthreads();
    if (threadIdx.x == 0) {
        double S = shs[0] + shs[1] + shs[2] + shs[3];
        double Q = shq[0] + shq[1] + shq[2] + shq[3];
        double m = S / 2048.0;
        double var = Q / 2048.0 - m * m;
        mu[row] = (float)m;
        rstd[row] = (float)(1.0 / sqrt(var + 1e-5));
    }
}

// S[n] = sum_k W[n,k] (f32 W); one wave per row, 4 rows per block (fallback)
__global__ void rowsum_kernel(const float* __restrict__ W,
                              float* __restrict__ S, int K) {
    const int lane = threadIdx.x & 63, w = threadIdx.x >> 6;
    const int row = blockIdx.x * 4 + w;
    const float* p = W + (size_t)row * K;
    double s = 0.0;
    for (int c = lane * 8; c < K; c += 512) {
#pragma unroll
        for (int i = 0; i < 8; ++i) s += p[c + i];
    }
    for (int o = 32; o > 0; o >>= 1) s += __shfl_down(s, o, 64);
    if (lane == 0) S[row] = (float)s;
}

// [R,C] f32 -> [R,2C] bf16 as [hi | lo]; one block per row, C = 2048 (fallback)
__global__ void split2_kernel(const float* __restrict__ src,
                              unsigned short* __restrict__ dst, int C) {
    const int r = blockIdx.x;
    const int c = threadIdx.x * 8;
    const float* p = src + (size_t)r * C + c;
    float4 u0 = ((const float4*)p)[0];
    float4 u1 = ((const float4*)p)[1];
    float v[8] = {u0.x, u0.y, u0.z, u0.w, u1.x, u1.y, u1.z, u1.w};
    unsigned short hi[8], lo[8];
#pragma unroll
    for (int i = 0; i < 8; ++i) {
        hi[i] = f2b(v[i]);
        lo[i] = f2b(v[i] - b2f(hi[i]));
    }
    unsigned short* d = dst + (size_t)r * 2 * C + c;
    *(uint4*)d = *(const uint4*)hi;
    *(uint4*)(d + C) = *(const uint4*)lo;
}

// ============================================================================
// pre_all: fused preprocessing, ONE launch (round-7 proven).
// blocks [0,1024):    x row r -> LN stats + hi|lo split into Asplit.
// blocks [1024,5120): W1 row r -> row sum (fp64) into S1 + hi|lo split -> W1b.
// ============================================================================
__global__ void pre_all(const float* __restrict__ x, const float* __restrict__ W1,
                        float* __restrict__ mu, float* __restrict__ rstd,
                        float* __restrict__ S1,
                        unsigned short* __restrict__ Asplit,
                        unsigned short* __restrict__ W1b) {
    const int tid = threadIdx.x;
    const int lane = tid & 63, w = tid >> 6;
    const int c = tid * 8;
    __shared__ double shs[4], shq[4];
    if (blockIdx.x < 1024) {
        const int r = blockIdx.x;
        const float* p = x + (size_t)r * 2048 + c;
        float4 u0 = ((const float4*)p)[0];
        float4 u1 = ((const float4*)p)[1];
        float v[8] = {u0.x, u0.y, u0.z, u0.w, u1.x, u1.y, u1.z, u1.w};
        double s = 0.0, q = 0.0;
#pragma unroll
        for (int i = 0; i < 8; ++i) { s += v[i]; q += (double)v[i] * v[i]; }
        for (int o = 32; o > 0; o >>= 1) { s += __shfl_down(s, o, 64); q += __shfl_down(q, o, 64); }
        if (lane == 0) { shs[w] = s; shq[w] = q; }
        __syncthreads();
        if (tid == 0) {
            double S = shs[0] + shs[1] + shs[2] + shs[3];
            double Q = shq[0] + shq[1] + shq[2] + shq[3];
            double m = S / 2048.0;
            double var = Q / 2048.0 - m * m;
            mu[r] = (float)m;
            rstd[r] = (float)(1.0 / sqrt(var + 1e-5));
        }
        unsigned short hi[8], lo[8];
#pragma unroll
        for (int i = 0; i < 8; ++i) {
            hi[i] = f2b(v[i]);
            lo[i] = f2b(v[i] - b2f(hi[i]));
        }
        unsigned short* d = Asplit + (size_t)r * 4096 + c;
        *(uint4*)d = *(const uint4*)hi;
        *(uint4*)(d + 2048) = *(const uint4*)lo;
    } else {
        const int r = blockIdx.x - 1024;
        const float* p = W1 + (size_t)r * 2048 + c;
        float4 u0 = ((const float4*)p)[0];
        float4 u1 = ((const float4*)p)[1];
        float v[8] = {u0.x, u0.y, u0.z, u0.w, u1.x, u1.y, u1.z, u1.w};
        double s = 0.0;
#pragma unroll
        for (int i = 0; i < 8; ++i) s += v[i];
        for (int o = 32; o > 0; o >>= 1) s += __shfl_down(s, o, 64);
        if (lane == 0) shs[w] = s;
        __syncthreads();
        if (tid == 0) S1[r] = (float)(shs[0] + shs[1] + shs[2] + shs[3]);
        unsigned short hi[8], lo[8];
#pragma unroll
        for (int i = 0; i < 8; ++i) {
            hi[i] = f2b(v[i]);
            lo[i] = f2b(v[i] - b2f(hi[i]));
        }
        unsigned short* d = W1b + (size_t)r * 4096 + c;
        *(uint4*)d = *(const uint4*)hi;
        *(uint4*)(d + 2048) = *(const uint4*)lo;
    }
}

// flat f32 -> bf16, 8 el/thread
__global__ void cvt_kernel(const float* __restrict__ src,
                           unsigned short* __restrict__ dst) {
    const size_t i = ((size_t)blockIdx.x * 256 + threadIdx.x) * 8;
    float4 u0 = ((const float4*)(src + i))[0];
    float4 u1 = ((const float4*)(src + i))[1];
    float v[8] = {u0.x, u0.y, u0.z, u0.w, u1.x, u1.y, u1.z, u1.w};
    unsigned short t[8];
#pragma unroll
    for (int q = 0; q < 8; ++q) t[q] = f2b(v[q]);
    *(uint4*)(dst + i) = *(const uint4*)t;
}

// two-range flat f32 -> bf16 in one launch (W3 + Wout): kills one launch.
__global__ void cvt2_kernel(const float* __restrict__ s1, unsigned short* __restrict__ d1,
                            int nb1, const float* __restrict__ s2,
                            unsigned short* __restrict__ d2) {
    const int b = blockIdx.x;
    const float* src = (b < nb1) ? s1 : s2;
    unsigned short* dst = (b < nb1) ? d1 : d2;
    const int bb = (b < nb1) ? b : b - nb1;
    const size_t i = ((size_t)bb * 256 + threadIdx.x) * 8;
    float4 u0 = ((const float4*)(src + i))[0];
    float4 u1 = ((const float4*)(src + i))[1];
    float v[8] = {u0.x, u0.y, u0.z, u0.w, u1.x, u1.y, u1.z, u1.w};
    unsigned short t[8];
#pragma unroll
    for (int q = 0; q < 8; ++q) t[q] = f2b(v[q]);
    *(uint4*)(dst + i) = *(const uint4*)t;
}

// ============================================================================
// gemm_kan1: L1 FUSED hi/lo kernel, v2 (round-9 post-mortem fix).
// Per K=32 logical slice: 3 MFMA groups hi*hi + lo*hi + hi*lo, operands
// staged ONCE (24 KB vs round-7's 36 KB per logical slice).
// *** LDS layout fix vs round 9 (6.3M bank conflicts): 128-B rows. ***
// Row r holds [hi(k0..k0+31) | lo(k0..k0+31)] = 64 shorts -> row stride is
// a full bank rotation, and the 8x16B-slot XOR swizzle (phys = logical ^
// (row&7)) is BYTE-IDENTICAL to the round-3 kernel's measured-0-conflict
// pattern (read addr: ((s*4+kq)^(fr&7))*16B, s=0 hi / s=1 lo).
// Staging source col for phys (r,u): v = u^(r&7); col = (v&3)*8 +
// (v>>2)*2048 + k0  (hi and lo both advance +32/tile -> one base offset).
// Schedule: proven counted-vmcnt(6) triple-buffer 2-deep, 1 barrier/tile.
// BM=64 BN=128, 4 waves 2x2, acc[2][4]; 512 blocks = 2 blocks/CU.
// Epilogue: lin = rstd*(acc - mu*S1) + bias, KAN+NCT, bf16 out.
// ============================================================================
__global__ __launch_bounds__(256, 2)
void gemm_kan1(const unsigned short* __restrict__ Ab,
               const unsigned short* __restrict__ Bb,
               const float* __restrict__ bias, const float* __restrict__ cp,
               const float* __restrict__ rw, const float* __restrict__ mu,
               const float* __restrict__ rstd, const float* __restrict__ S1,
               unsigned short* __restrict__ outp,
               int Nld, int Klog, int lda, int ldb)
{
    constexpr int BM = 64, BN = 128;
    constexpr int ABASE = 0, BBASE = 4096;   // shorts; A 64x64, B 128x64
    constexpr int BUF = 12288;               // 24 KB in shorts
    __shared__ unsigned short lds[3 * BUF];  // 72 KB triple buffer

    const int tid  = threadIdx.x;
    const int lane = tid & 63;
    const int wid  = tid >> 6;

    // XCD-chunked bijective swizzle (nwg = 512, %8==0)
    const int gx = gridDim.x;
    int flat = blockIdx.y * gx + blockIdx.x;
    const int nwg = gx * gridDim.y;
    if ((nwg & 7) == 0) flat = (flat & 7) * (nwg >> 3) + (flat >> 3);
    const int bm = (flat % gx) * BM;
    const int bn = (flat / gx) * BN;

    const int wmo = (wid >> 1) * 32;   // wave row offset within BM
    const int wno = (wid & 1) * 64;    // wave col offset within BN
    const int fr = lane & 15;
    const int kq = lane >> 4;
    const int sxr = fr & 7;            // read-side XOR term (row & 7)

    // staging unit u: LDS linear dest = u*16B (row u>>3, phys slot u&7);
    // logical slot v = (u&7)^(row&7); source col = (v&3)*8 + (v>>2)*2048.
    const int uA0 = (wid << 7) + lane;          // A: 512 units, 2 per thread
    const int uA1 = uA0 + 64;
    const int uB0 = (wid << 8) + lane;          // B: 1024 units, 4 per thread
    const int uB1 = uB0 + 64, uB2 = uB0 + 128, uB3 = uB0 + 192;
#define VLOG(u) ((((u) & 7)) ^ (((u) >> 3) & 7))
#define SRCC(u) (((VLOG(u) & 3) << 3) + ((VLOG(u) >> 2) * 2048))
    const size_t aoff0 = (size_t)(bm + (uA0 >> 3)) * lda + SRCC(uA0);
    const size_t aoff1 = (size_t)(bm + (uA1 >> 3)) * lda + SRCC(uA1);
    const size_t boff0 = (size_t)(bn + (uB0 >> 3)) * ldb + SRCC(uB0);
    const size_t boff1 = (size_t)(bn + (uB1 >> 3)) * ldb + SRCC(uB1);
    const size_t boff2 = (size_t)(bn + (uB2 >> 3)) * ldb + SRCC(uB2);
    const size_t boff3 = (size_t)(bn + (uB3 >> 3)) * ldb + SRCC(uB3);
#undef SRCC
#undef VLOG

    f32x4 acc[2][4] = {};

#define STAGE(BSEL, K) do {                                           \
    unsigned short* l_ = &lds[(BSEL) * BUF];                          \
    gl16(l_ + ABASE + uA0 * 8, Ab + aoff0 + (K));                     \
    gl16(l_ + ABASE + uA1 * 8, Ab + aoff1 + (K));                     \
    gl16(l_ + BBASE + uB0 * 8, Bb + boff0 + (K));                     \
    gl16(l_ + BBASE + uB1 * 8, Bb + boff1 + (K));                     \
    gl16(l_ + BBASE + uB2 * 8, Bb + boff2 + (K));                     \
    gl16(l_ + BBASE + uB3 * 8, Bb + boff3 + (K));                     \
} while (0)

    const int nt = Klog / 32;          // 64 tiles of logical K=32
    STAGE(0, 0);
    STAGE(1, 32);

    for (int t = 0; t < nt; ++t) {
        // counted drain: most recent STAGE (6 loads) stays in flight across
        // the barrier; own t-tile loads (issued 2 iters ago) are complete.
        if (t + 1 < nt) asm volatile("s_waitcnt vmcnt(6)" ::: "memory");
        else            asm volatile("s_waitcnt vmcnt(0)" ::: "memory");
        __builtin_amdgcn_s_barrier();
        __builtin_amdgcn_sched_barrier(0);  // pin ds_reads below the barrier
        if (t + 2 < nt) STAGE((t + 2) % 3, (t + 2) * 32);
        const unsigned short* cl = &lds[(t % 3) * BUF];
        const int slH = ((kq ^ sxr)) << 3;        // hi: logical slot kq
        const int slL = (((4 + kq) ^ sxr)) << 3;  // lo: logical slot 4+kq
        bf16x8 aH[2], aL[2], bH[4], bL[4];
#pragma unroll
        for (int i = 0; i < 2; ++i) {
            const int ro = ABASE + (wmo + i * 16 + fr) * 64;
            aH[i] = *(const bf16x8*)&cl[ro + slH];
            aL[i] = *(const bf16x8*)&cl[ro + slL];
        }
#pragma unroll
        for (int j = 0; j < 4; ++j) {
            const int ro = BBASE + (wno + j * 16 + fr) * 64;
            bH[j] = *(const bf16x8*)&cl[ro + slH];
            bL[j] = *(const bf16x8*)&cl[ro + slL];
        }
#pragma unroll
        for (int i = 0; i < 2; ++i)
#pragma unroll
            for (int j = 0; j < 4; ++j)
                acc[i][j] = __builtin_amdgcn_mfma_f32_16x16x32_bf16(aH[i], bH[j], acc[i][j], 0, 0, 0);
#pragma unroll
        for (int i = 0; i < 2; ++i)
#pragma unroll
            for (int j = 0; j < 4; ++j)
                acc[i][j] = __builtin_amdgcn_mfma_f32_16x16x32_bf16(aL[i], bH[j], acc[i][j], 0, 0, 0);
#pragma unroll
        for (int i = 0; i < 2; ++i)
#pragma unroll
            for (int j = 0; j < 4; ++j)
                acc[i][j] = __builtin_amdgcn_mfma_f32_16x16x32_bf16(aH[i], bL[j], acc[i][j], 0, 0, 0);
    }
#undef STAGE

    // ---- epilogue: C layout col = lane&15, row = (lane>>4)*4 + reg ----
    const int rowg = (lane >> 4) * 4;
#pragma unroll
    for (int j = 0; j < 4; ++j) {
        const int n = bn + wno + j * 16 + fr;
        const float bs = bias[n];
        float cpf[8];
#pragma unroll
        for (int q = 0; q < 8; ++q) cpf[q] = cp[(size_t)n * 9 + q];
        const float rwf = rw[n];
        const float s1 = S1[n];
        const int s = n & 7;  // generator slot: {0,1}->sx, {2,3}->sy, {4..7}->identity
#pragma unroll
        for (int i = 0; i < 2; ++i) {
            const int m0 = bm + wmo + i * 16 + rowg;
#pragma unroll
            for (int r = 0; r < 4; ++r) {
                const int m = m0 + r;
                float v = acc[i][j][r];
                v = (v - mu[m] * s1) * rstd[m] + bs;
                v = kan_spline(tanhf(v), cpf, rwf);
                float p = __shfl_xor(v, 1, 64);  // partner col n^1 lives in lane^1
                p = fminf(fmaxf(p, -1.0f), 1.0f);
                if (s < 4) v += ((s == 2) ? -0.05f : 0.05f) * p;
                outp[(size_t)m * Nld + n] = f2b(v);
            }
        }
    }
}

// ============================================================================
// gemm_kan2: ROUND-3 EXACT core (measured 79.5 us, reproduced 4x).
// C[1024 x Ncols] = A @ B^T, bf16 inputs, fused LN-fold/KAN/NCT.
// BM=64 BN=128 BK=64, 4 waves 2x2 (wave tile 32x64, acc[2][4]); 512-block
// grids = 2 blocks/CU where possible. Triple-buffered LDS (72 KB), 2-deep
// global_load_lds prefetch, ONE raw s_barrier per K-step preceded by COUNTED
// s_waitcnt vmcnt(6). sched_barrier pins ds_reads below the barrier. XOR
// bank-conflict swizzle source+read side, LDS dest linear (0 conflicts).
// XCD-chunked grid swizzle.
// EPI 0: lin = rstd*(acc - mu*S1) + bias, KAN+NCT, bf16 out (Ktot=6144
//        mapped: seg0 hi*hi, seg1 lo*hi, seg2 hi*lo — HALF path only).
// EPI 1: acc+bias, KAN+NCT, bf16.  EPI 2: acc+bias, f32.
// ============================================================================
template <int EPI>
__global__ __launch_bounds__(256, 2)
void gemm_kan2(const unsigned short* __restrict__ Ab,
               const unsigned short* __restrict__ Bb,
               const float* __restrict__ bias, const float* __restrict__ cp,
               const float* __restrict__ rw, const float* __restrict__ mu,
               const float* __restrict__ rstd, const float* __restrict__ S1,
               void* __restrict__ outp,
               int Nld, int n0, int Ktot, int lda, int ldb)
{
    constexpr int BM = 64, BN = 128, BK = 64;
    constexpr int ASZ = BM * BK;        // 4096 shorts = 8 KB
    constexpr int BUF = ASZ + BN * BK;  // 12288 shorts = 24 KB
    __shared__ unsigned short lds[3 * BUF];  // 72 KB triple buffer

    const int tid  = threadIdx.x;
    const int lane = tid & 63;
    const int wid  = tid >> 6;

    // XCD-chunked bijective swizzle (nwg % 8 == 0 for every launch here)
    const int gx = gridDim.x;
    int flat = blockIdx.y * gx + blockIdx.x;
    const int nwg = gx * gridDim.y;
    if ((nwg & 7) == 0) flat = (flat & 7) * (nwg >> 3) + (flat >> 3);
    const int bm = (flat % gx) * BM;
    const int bn = (flat / gx) * BN;

    const int wmo = (wid >> 1) * 32;   // wave row offset within BM
    const int wno = (wid & 1) * 64;    // wave col offset within BN
    const int fr = lane & 15;
    const int kq = lane >> 4;
    const int sxr = fr & 7;            // read-side XOR term (row & 7)

    // staging unit u: LDS linear dest = u*16B (row u>>3, 16B-slot u&7);
    // global source slot = (u&7) ^ (row&7)   [inverse swizzle on source]
    const int uA0 = (wid << 7) + lane;          // A: 512 units, 2 per thread
    const int uA1 = uA0 + 64;
    const int uB0 = (wid << 8) + lane;          // B: 1024 units, 4 per thread
    const int uB1 = uB0 + 64, uB2 = uB0 + 128, uB3 = uB0 + 192;
#define SRCOL(u) (((((u) & 7) ^ (((u) >> 3) & 7))) << 3)
    const size_t aoff0 = (size_t)(bm + (uA0 >> 3)) * lda + SRCOL(uA0);
    const size_t aoff1 = (size_t)(bm + (uA1 >> 3)) * lda + SRCOL(uA1);
    const size_t boff0 = (size_t)(bn + (uB0 >> 3)) * ldb + SRCOL(uB0);
    const size_t boff1 = (size_t)(bn + (uB1 >> 3)) * ldb + SRCOL(uB1);
    const size_t boff2 = (size_t)(bn + (uB2 >> 3)) * ldb + SRCOL(uB2);
    const size_t boff3 = (size_t)(bn + (uB3 >> 3)) * ldb + SRCOL(uB3);
#undef SRCOL

    f32x4 acc[2][4] = {};

#define STAGE(BSEL, AK, BKK) do {                                     \
    unsigned short* lA_ = &lds[(BSEL) * BUF];                         \
    unsigned short* lB_ = lA_ + ASZ;                                  \
    gl16(lA_ + uA0 * 8, Ab + aoff0 + (AK));                           \
    gl16(lA_ + uA1 * 8, Ab + aoff1 + (AK));                           \
    gl16(lB_ + uB0 * 8, Bb + boff0 + (BKK));                          \
    gl16(lB_ + uB1 * 8, Bb + boff1 + (BKK));                          \
    gl16(lB_ + uB2 * 8, Bb + boff2 + (BKK));                          \
    gl16(lB_ + uB3 * 8, Bb + boff3 + (BKK));                          \
} while (0)

    const int nt = Ktot / BK;
    STAGE(0, 0, 0);
    STAGE(1, BK, BK);   // kn=64 < 2048: no segment remap needed at any EPI

    for (int t = 0; t < nt; ++t) {
        // counted drain: allow the (t+1)-tile STAGE (6 loads) to stay in
        // flight across the barrier; own t-tile loads are then complete.
        if (t + 1 < nt) asm volatile("s_waitcnt vmcnt(6)" ::: "memory");
        else            asm volatile("s_waitcnt vmcnt(0)" ::: "memory");
        __builtin_amdgcn_s_barrier();
        __builtin_amdgcn_sched_barrier(0);  // pin ds_reads below the barrier
        if (t + 2 < nt) {
            const int kn = (t + 2) * BK;
            int ak = kn, bk = kn;
            if (EPI == 0) {
                ak = (kn < 4096) ? kn : kn - 4096;
                bk = (kn < 2048) ? kn : kn - 2048;
            }
            STAGE((t + 2) % 3, ak, bk);
        }
        const unsigned short* cl = &lds[(t % 3) * BUF];
#pragma unroll
        for (int s = 0; s < 2; ++s) {
            const int sl = ((((s << 2) + kq) ^ sxr)) << 3;  // swizzled 16B slot
            bf16x8 aF[2], bF[4];
#pragma unroll
            for (int i = 0; i < 2; ++i)
                aF[i] = *(const bf16x8*)&cl[(wmo + i * 16 + fr) * BK + sl];
#pragma unroll
            for (int j = 0; j < 4; ++j)
                bF[j] = *(const bf16x8*)&cl[ASZ + (wno + j * 16 + fr) * BK + sl];
#pragma unroll
            for (int i = 0; i < 2; ++i)
#pragma unroll
                for (int j = 0; j < 4; ++j)
                    acc[i][j] = __builtin_amdgcn_mfma_f32_16x16x32_bf16(aF[i], bF[j], acc[i][j], 0, 0, 0);
        }
    }
#undef STAGE

    // ---- epilogue: C layout col = lane&15, row = (lane>>4)*4 + reg ----
    const int rowg = (lane >> 4) * 4;
#pragma unroll
    for (int j = 0; j < 4; ++j) {
        const int n = n0 + bn + wno + j * 16 + fr;
        const float bs = bias[n];
        float cpf[8], rwf = 0.0f, s1 = 0.0f;
        if (EPI < 2) {
#pragma unroll
            for (int q = 0; q < 8; ++q) cpf[q] = cp[(size_t)n * 9 + q];
            rwf = rw[n];
        }
        if (EPI == 0) s1 = S1[n];
        const int s = n & 7;  // generator slot: {0,1}->sx, {2,3}->sy, {4..7}->identity
#pragma unroll
        for (int i = 0; i < 2; ++i) {
            const int m0 = bm + wmo + i * 16 + rowg;
#pragma unroll
            for (int r = 0; r < 4; ++r) {
                const int m = m0 + r;
                float v = acc[i][j][r];
                if (EPI == 0) v = (v - mu[m] * s1) * rstd[m] + bs;
                else          v += bs;
                if (EPI < 2) {
                    v = kan_spline(tanhf(v), cpf, rwf);
                    float p = __shfl_xor(v, 1, 64);  // partner col n^1 lives in lane^1
                    p = fminf(fmaxf(p, -1.0f), 1.0f);
                    if (s < 4) v += ((s == 2) ? -0.05f : 0.05f) * p;
                }
                if (EPI == 2) ((float*)outp)[(size_t)m * Nld + n] = v;
                else ((unsigned short*)outp)[(size_t)m * Nld + n] = f2b(v);
            }
        }
    }
}

// ============================================================================
// Legacy 64x64 kernel kept ONLY for the small-workspace insurance path
// (in-loop f32->bf16 conversion variants BSRC 1/2). Unchanged.
// ============================================================================
template <int EPI, int BSRC>
__global__ __launch_bounds__(256, 2)
void gemm_kan(const void* __restrict__ Av, const void* __restrict__ Bv,
              const float* __restrict__ bias, const float* __restrict__ cp,
              const float* __restrict__ rw, const float* __restrict__ mu,
              const float* __restrict__ rstd, const float* __restrict__ S1,
              void* __restrict__ outp,
              int Nld, int n0, int Ktot, int lda, int ldb)
{
    constexpr int BM = 64, BN = 64, BK = 64, LDP = 72;
    constexpr bool SPL = (BSRC == 2);
    constexpr int OFF_B  = BM * LDP;
    constexpr int OFF_LO = (BM + BN) * LDP;
    __shared__ unsigned short lds[(SPL ? 2 : 1) * (BM + BN) * LDP];

    const int tid  = threadIdx.x;
    const int lane = tid & 63;
    const int wid  = tid >> 6;
    const int bm = blockIdx.x * BM;
    const int bn = blockIdx.y * BN;
    const int wmo = (wid >> 1) * 32;
    const int wno = (wid & 1) * 32;
    const int fr = lane & 15;
    const int kq = lane >> 4;
    const int sar = tid >> 3, sac = (tid & 7) << 3;
    const int sfr = tid >> 2, sfc = (tid & 3) << 4;

    f32x4 acc[2][2] = {};

    uint4 pA0 = {}, pA1 = {}, pB0 = {}, pB1 = {};
    const unsigned short* Ab = (const unsigned short*)Av;
    const unsigned short* Bb = (const unsigned short*)Bv;
    const size_t a0 = (size_t)(bm + sar) * lda + sac;
    const size_t a1 = (size_t)(bm + 32 + sar) * lda + sac;
    const size_t b0 = (size_t)(bn + sar) * ldb + sac;
    const size_t b1 = (size_t)(bn + 32 + sar) * ldb + sac;
    if constexpr (BSRC == 0) {
        pA0 = *(const uint4*)(Ab + a0);
        pA1 = *(const uint4*)(Ab + a1);
        pB0 = *(const uint4*)(Bb + b0);
        pB1 = *(const uint4*)(Bb + b1);
    }

    for (int k0 = 0; k0 < Ktot; k0 += BK) {
        if constexpr (BSRC == 0) {
            *(uint4*)&lds[sar * LDP + sac] = pA0;
            *(uint4*)&lds[(32 + sar) * LDP + sac] = pA1;
            *(uint4*)&lds[OFF_B + sar * LDP + sac] = pB0;
            *(uint4*)&lds[OFF_B + (32 + sar) * LDP + sac] = pB1;
        } else {
            {
                const float* g = (const float*)Bv + (size_t)(bn + sfr) * ldb + k0 + sfc;
                float4 u0 = ((const float4*)g)[0];
                float4 u1 = ((const float4*)g)[1];
                float4 u2 = ((const float4*)g)[2];
                float4 u3 = ((const float4*)g)[3];
                float v[16] = {u0.x,u0.y,u0.z,u0.w, u1.x,u1.y,u1.z,u1.w,
                               u2.x,u2.y,u2.z,u2.w, u3.x,u3.y,u3.z,u3.w};
                unsigned short hi[16], lo[16];
#pragma unroll
                for (int i = 0; i < 16; ++i) {
                    hi[i] = f2b(v[i]);
                    if (SPL) lo[i] = f2b(v[i] - b2f(hi[i]));
                }
                unsigned short* d = &lds[OFF_B + sfr * LDP + sfc];
                ((uint4*)d)[0] = *(const uint4*)&hi[0];
                ((uint4*)d)[1] = *(const uint4*)&hi[8];
                if constexpr (SPL) {
                    unsigned short* dl = d + OFF_LO;
                    ((uint4*)dl)[0] = *(const uint4*)&lo[0];
                    ((uint4*)dl)[1] = *(const uint4*)&lo[8];
                }
            }
            if constexpr (SPL) {
                const float* g = (const float*)Av + (size_t)(bm + sfr) * lda + k0 + sfc;
                float4 u0 = ((const float4*)g)[0];
                float4 u1 = ((const float4*)g)[1];
                float4 u2 = ((const float4*)g)[2];
                float4 u3 = ((const float4*)g)[3];
                float v[16] = {u0.x,u0.y,u0.z,u0.w, u1.x,u1.y,u1.z,u1.w,
                               u2.x,u2.y,u2.z,u2.w, u3.x,u3.y,u3.z,u3.w};
                unsigned short hi[16], lo[16];
#pragma unroll
                for (int i = 0; i < 16; ++i) {
                    hi[i] = f2b(v[i]);
                    lo[i] = f2b(v[i] - b2f(hi[i]));
                }
                unsigned short* d = &lds[sfr * LDP + sfc];
                ((uint4*)d)[0] = *(const uint4*)&hi[0];
                ((uint4*)d)[1] = *(const uint4*)&hi[8];
                unsigned short* dl = d + OFF_LO;
                ((uint4*)dl)[0] = *(const uint4*)&lo[0];
                ((uint4*)dl)[1] = *(const uint4*)&lo[8];
            } else {
                *(uint4*)&lds[sar * LDP + sac] = *(const uint4*)(Ab + a0 + k0);
                *(uint4*)&lds[(32 + sar) * LDP + sac] = *(const uint4*)(Ab + a1 + k0);
            }
        }
        __syncthreads();
        if constexpr (BSRC == 0) {
            if (k0 + BK < Ktot) {
                const int kn = k0 + BK;
                const int ak = (EPI == 0) ? (kn < 4096 ? kn : kn - 4096) : kn;
                const int bk = (EPI == 0) ? (kn < 2048 ? kn : kn - 2048) : kn;
                pA0 = *(const uint4*)(Ab + a0 + ak);
                pA1 = *(const uint4*)(Ab + a1 + ak);
                pB0 = *(const uint4*)(Bb + b0 + bk);
                pB1 = *(const uint4*)(Bb + b1 + bk);
            }
        }
#pragma unroll
        for (int s = 0; s < 2; ++s) {
            const int cc = (s * 4 + kq) << 3;
            bf16x8 aF[2], bF[2];
#pragma unroll
            for (int i = 0; i < 2; ++i)
                aF[i] = *(const bf16x8*)&lds[(wmo + i * 16 + fr) * LDP + cc];
#pragma unroll
            for (int j = 0; j < 2; ++j)
                bF[j] = *(const bf16x8*)&lds[OFF_B + (wno + j * 16 + fr) * LDP + cc];
#pragma unroll
            for (int i = 0; i < 2; ++i)
#pragma unroll
                for (int j = 0; j < 2; ++j)
                    acc[i][j] = __builtin_amdgcn_mfma_f32_16x16x32_bf16(aF[i], bF[j], acc[i][j], 0, 0, 0);
            if constexpr (SPL) {
                bf16x8 aL[2], bL[2];
#pragma unroll
                for (int i = 0; i < 2; ++i)
                    aL[i] = *(const bf16x8*)&lds[OFF_LO + (wmo + i * 16 + fr) * LDP + cc];
#pragma unroll
                for (int i = 0; i < 2; ++i)
#pragma unroll
                    for (int j = 0; j < 2; ++j)
                        acc[i][j] = __builtin_amdgcn_mfma_f32_16x16x32_bf16(aL[i], bF[j], acc[i][j], 0, 0, 0);
#pragma unroll
                for (int j = 0; j < 2; ++j)
                    bL[j] = *(const bf16x8*)&lds[OFF_LO + OFF_B + (wno + j * 16 + fr) * LDP + cc];
#pragma unroll
                for (int i = 0; i < 2; ++i)
#pragma unroll
                    for (int j = 0; j < 2; ++j)
                        acc[i][j] = __builtin_amdgcn_mfma_f32_16x16x32_bf16(aF[i], bL[j], acc[i][j], 0, 0, 0);
            }
        }
        __syncthreads();
    }

    const int rowg = (lane >> 4) * 4;
#pragma unroll
    for (int j = 0; j < 2; ++j) {
        const int n = n0 + bn + wno + j * 16 + fr;
        const float bs = bias[n];
        float cpf[8], rwf = 0.0f, s1 = 0.0f;
        if (EPI < 2) {
#pragma unroll
            for (int q = 0; q < 8; ++q) cpf[q] = cp[(size_t)n * 9 + q];
            rwf = rw[n];
        }
        if (EPI == 0) s1 = S1[n];
        const int s = n & 7;
#pragma unroll
        for (int i = 0; i < 2; ++i) {
            const int m0 = bm + wmo + i * 16 + rowg;
#pragma unroll
            for (int r = 0; r < 4; ++r) {
                const int m = m0 + r;
                float v = acc[i][j][r];
                if (EPI == 0) v = (v - mu[m] * s1) * rstd[m] + bs;
                else          v += bs;
                if (EPI < 2) {
                    v = kan_spline(tanhf(v), cpf, rwf);
                    float p = __shfl_xor(v, 1, 64);
                    p = fminf(fmaxf(p, -1.0f), 1.0f);
                    if (s < 4) v += ((s == 2) ? -0.05f : 0.05f) * p;
                }
                if (EPI == 2) ((float*)outp)[(size_t)m * Nld + n] = v;
                else ((unsigned short*)outp)[(size_t)m * Nld + n] = f2b(v);
            }
        }
    }
}

extern "C" void kernel_launch(void* const* d_in, const int* in_sizes, int n_in,
                              void* d_out, int out_size, void* d_ws, size_t ws_size,
                              hipStream_t stream) {
    const float* x    = (const float*)d_in[0];
    const float* W1   = (const float*)d_in[1];
    const float* b1   = (const float*)d_in[2];
    const float* cp1  = (const float*)d_in[3];
    const float* rw1  = (const float*)d_in[4];
    const float* W2   = (const float*)d_in[5];
    const float* b2   = (const float*)d_in[6];
    const float* cp2  = (const float*)d_in[7];
    const float* rw2  = (const float*)d_in[8];
    const float* W3   = (const float*)d_in[9];
    const float* b3   = (const float*)d_in[10];
    const float* cp3  = (const float*)d_in[11];
    const float* rw3  = (const float*)d_in[12];
    const float* Wout = (const float*)d_in[13];
    const float* bout = (const float*)d_in[14];

    char* ws = (char*)d_ws;
    float* mu   = (float*)(ws);                  // 1024 f32
    float* rstd = (float*)(ws + 4096);           // 1024 f32
    float* S1   = (float*)(ws + 8192);           // 4096 f32
    unsigned short* A2 = (unsigned short*)(ws + 32768);              // 1024x4096 bf16 (8MB)
    unsigned short* A3 = (unsigned short*)(ws + 32768 + 8388608);    // 1024x4096 bf16 (8MB)
    unsigned short* A4 = A2;                      // A2 dead after L2 gemm
    unsigned short* Asplit = A3;                  // x split lives in A3 slot until L2 writes it
    unsigned short* Wb = (unsigned short*)(ws + 32768 + 2 * 8388608); // 32MB region
    const size_t NEED_FULL = 32768 + 2 * 8388608 + 33554432;  // 50.4 MB
    const size_t NEED_HALF = 32768 + 2 * 8388608 + 16777216;  // 33.6 MB

    if (ws_size >= NEED_FULL) {
        // 7 launches (round-7 structure; L1 uses the fused hi/lo kernel v2).
        pre_all<<<5120, 256, 0, stream>>>(x, W1, mu, rstd, S1, Asplit, Wb);
        gemm_kan1<<<dim3(16, 32), 256, 0, stream>>>(
            Asplit, Wb, b1, cp1, rw1, mu, rstd, S1, A2, 4096, 2048, 4096, 4096);
        cvt_kernel<<<8192, 256, 0, stream>>>(W2, Wb);
        gemm_kan2<1><<<dim3(16, 32), 256, 0, stream>>>(
            A2, Wb, b2, cp2, rw2, nullptr, nullptr, nullptr, A3, 4096, 0, 4096, 4096, 4096);
        cvt2_kernel<<<6144, 256, 0, stream>>>(W3, Wb, 4096, Wout, Wb + 8388608);
        gemm_kan2<1><<<dim3(16, 16), 256, 0, stream>>>(
            A3, Wb, b3, cp3, rw3, nullptr, nullptr, nullptr, A4, 2048, 0, 4096, 4096, 4096);
        gemm_kan2<2><<<dim3(16, 16), 256, 0, stream>>>(
            A4, Wb + 8388608, bout, nullptr, nullptr, nullptr, nullptr, nullptr, d_out, 2048, 0, 2048, 2048, 2048);
    } else if (ws_size >= NEED_HALF) {
        ln_stats_kernel<<<1024, 256, 0, stream>>>(x, mu, rstd);
        rowsum_kernel<<<1024, 256, 0, stream>>>(W1, S1, 2048);
        split2_kernel<<<1024, 256, 0, stream>>>(x, Asplit, 2048);
        for (int h = 0; h < 2; ++h) {
            split2_kernel<<<2048, 256, 0, stream>>>(W1 + (size_t)h * 2048 * 2048, Wb, 2048);
            gemm_kan2<0><<<dim3(16, 16), 256, 0, stream>>>(
                Asplit, Wb, b1, cp1, rw1, mu, rstd, S1, A2, 4096, h * 2048, 6144, 4096, 4096);
        }
        for (int h = 0; h < 2; ++h) {
            cvt_kernel<<<4096, 256, 0, stream>>>(W2 + (size_t)h * 2048 * 4096, Wb);
            gemm_kan2<1><<<dim3(16, 16), 256, 0, stream>>>(
                A2, Wb, b2, cp2, rw2, nullptr, nullptr, nullptr, A3, 4096, h * 2048, 4096, 4096, 4096);
        }
        cvt_kernel<<<4096, 256, 0, stream>>>(W3, Wb);
        gemm_kan2<1><<<dim3(16, 16), 256, 0, stream>>>(
            A3, Wb, b3, cp3, rw3, nullptr, nullptr, nullptr, A4, 2048, 0, 4096, 4096, 4096);
        cvt_kernel<<<2048, 256, 0, stream>>>(Wout, Wb);
        gemm_kan2<2><<<dim3(16, 16), 256, 0, stream>>>(
            A4, Wb, bout, nullptr, nullptr, nullptr, nullptr, nullptr, d_out, 2048, 0, 2048, 2048, 2048);
    } else {
        // 16.8 MB insurance path: in-loop conversion (round-4-proven staging)
        ln_stats_kernel<<<1024, 256, 0, stream>>>(x, mu, rstd);
        rowsum_kernel<<<1024, 256, 0, stream>>>(W1, S1, 2048);
        gemm_kan<0, 2><<<dim3(16, 64), 256, 0, stream>>>(
            x, W1, b1, cp1, rw1, mu, rstd, S1, A2, 4096, 0, 2048, 2048, 2048);
        gemm_kan<1, 1><<<dim3(16, 64), 256, 0, stream>>>(
            A2, W2, b2, cp2, rw2, nullptr, nullptr, nullptr, A3, 4096, 0, 4096, 4096, 4096);
        gemm_kan<1, 1><<<dim3(16, 32), 256, 0, stream>>>(
            A3, W3, b3, cp3, rw3, nullptr, nullptr, nullptr, A4, 2048, 0, 4096, 4096, 4096);
        gemm_kan<2, 1><<<dim3(16, 32), 256, 0, stream>>>(
            A4, Wout, bout, nullptr, nullptr, nullptr, nullptr, nullptr, d_out, 2048, 0, 2048, 2048, 2048);
    }
}

// Round 11
// 377.512 us; speedup vs baseline: 1.0205x; 1.0205x over previous
//
#include <hip/hip_runtime.h>

typedef __attribute__((ext_vector_type(8))) short bf16x8;
typedef __attribute__((ext_vector_type(4))) float f32x4;

__device__ __forceinline__ float b2f(unsigned short u) {
    union { unsigned int i; float f; } x; x.i = ((unsigned int)u) << 16; return x.f;
}
__device__ __forceinline__ unsigned short f2b(float f) {
    union { float f; unsigned int i; } x; x.f = f;
    unsigned int r = x.i + 0x7fffu + ((x.i >> 16) & 1u);  // RNE
    return (unsigned short)(r >> 16);
}

// async global->LDS, 16 B per lane (wave-uniform LDS base + lane*16 layout)
__device__ __forceinline__ void gl16(unsigned short* l, const unsigned short* g) {
    __builtin_amdgcn_global_load_lds((__attribute__((address_space(1))) void*)g,
                                     (__attribute__((address_space(3))) void*)l, 16, 0, 0);
}

// Partial Cox-de Boor exactly as the reference leaves it:
// cols 0-4 degree 3, col 5 degree 2, col 6 degree 1, col 7 degree 0.
// knots = [-1,-1,-1,-1,-0.6,-0.2,0.2,0.6,1,1,1,1]
__device__ __forceinline__ float kan_spline(float t, const float* cpf, float rwf) {
    float c3 = (t >= -1.0f && t < -0.6f) ? 1.0f : 0.0f;
    float c4 = (t >= -0.6f && t < -0.2f) ? 1.0f : 0.0f;
    float c5 = (t >= -0.2f && t <  0.2f) ? 1.0f : 0.0f;
    float c6 = (t >=  0.2f && t <  0.6f) ? 1.0f : 0.0f;
    float c7 = (t >=  0.6f && t <  1.0f) ? 1.0f : 0.0f;
    float d2 = (-0.6f - t) * 2.5f * c3;
    float d3 = (t + 1.0f) * 2.5f * c3 + (-0.2f - t) * 2.5f * c4;
    float d4 = (t + 0.6f) * 2.5f * c4 + ( 0.2f - t) * 2.5f * c5;
    float d5 = (t + 0.2f) * 2.5f * c5 + ( 0.6f - t) * 2.5f * c6;
    float d6 = (t - 0.2f) * 2.5f * c6 + ( 1.0f - t) * 2.5f * c7;
    float e1 = (-0.6f - t) * 2.5f  * d2;
    float e2 = (t + 1.0f) * 2.5f  * d2 + (-0.2f - t) * 1.25f * d3;
    float e3 = (t + 1.0f) * 1.25f * d3 + ( 0.2f - t) * 1.25f * d4;
    float e4 = (t + 0.6f) * 1.25f * d4 + ( 0.6f - t) * 1.25f * d5;
    float e5 = (t + 0.2f) * 1.25f * d5 + ( 1.0f - t) * 1.25f * d6;
    const float r12 = 1.0f / 1.2f;
    float f0 = (-0.6f - t) * 2.5f  * e1;
    float f1 = (t + 1.0f) * 2.5f  * e1 + (-0.2f - t) * 1.25f * e2;
    float f2 = (t + 1.0f) * 1.25f * e2 + ( 0.2f - t) * r12   * e3;
    float f3 = (t + 1.0f) * r12   * e3 + ( 0.6f - t) * r12   * e4;
    float f4 = (t + 0.6f) * r12   * e4 + ( 1.0f - t) * r12   * e5;
    float sp = f0*cpf[0] + f1*cpf[1] + f2*cpf[2] + f3*cpf[3] + f4*cpf[4]
             + e5*cpf[5] + d6*cpf[6] + c7*cpf[7];
    float v = sp * rwf;
    return fminf(fmaxf(v, -10.0f), 10.0f);
}

// per-row mean / rstd of x[1024,2048] f32, fp64 accumulate (fallback paths)
__global__ void ln_stats_kernel(const float* __restrict__ x,
                                float* __restrict__ mu, float* __restrict__ rstd) {
    const int row = blockIdx.x;
    const float* p = x + (size_t)row * 2048 + threadIdx.x * 8;
    double s = 0.0, q = 0.0;
#pragma unroll
    for (int i = 0; i < 8; ++i) { float v = p[i]; s += v; q += (double)v * v; }
    for (int o = 32; o > 0; o >>= 1) { s += __shfl_down(s, o, 64); q += __shfl_down(q, o, 64); }
    __shared__ double shs[4], shq[4];
    const int lane = threadIdx.x & 63, w = threadIdx.x >> 6;
    if (lane == 0) { shs[w] = s; shq[w] = q; }
    __syncthreads();
    if (threadIdx.x == 0) {
        double S = shs[0] + shs[1] + shs[2] + shs[3];
        double Q = shq[0] + shq[1] + shq[2] + shq[3];
        double m = S / 2048.0;
        double var = Q / 2048.0 - m * m;
        mu[row] = (float)m;
        rstd[row] = (float)(1.0 / sqrt(var + 1e-5));
    }
}

// S[n] = sum_k W[n,k] (f32 W); one wave per row, 4 rows per block (fallback)
__global__ void rowsum_kernel(const float* __restrict__ W,
                              float* __restrict__ S, int K) {
    const int lane = threadIdx.x & 63, w = threadIdx.x >> 6;
    const int row = blockIdx.x * 4 + w;
    const float* p = W + (size_t)row * K;
    double s = 0.0;
    for (int c = lane * 8; c < K; c += 512) {
#pragma unroll
        for (int i = 0; i < 8; ++i) s += p[c + i];
    }
    for (int o = 32; o > 0; o >>= 1) s += __shfl_down(s, o, 64);
    if (lane == 0) S[row] = (float)s;
}

// [R,C] f32 -> [R,2C] bf16 as [hi | lo]; one block per row, C = 2048 (fallback)
__global__ void split2_kernel(const float* __restrict__ src,
                              unsigned short* __restrict__ dst, int C) {
    const int r = blockIdx.x;
    const int c = threadIdx.x * 8;
    const float* p = src + (size_t)r * C + c;
    float4 u0 = ((const float4*)p)[0];
    float4 u1 = ((const float4*)p)[1];
    float v[8] = {u0.x, u0.y, u0.z, u0.w, u1.x, u1.y, u1.z, u1.w};
    unsigned short hi[8], lo[8];
#pragma unroll
    for (int i = 0; i < 8; ++i) {
        hi[i] = f2b(v[i]);
        lo[i] = f2b(v[i] - b2f(hi[i]));
    }
    unsigned short* d = dst + (size_t)r * 2 * C + c;
    *(uint4*)d = *(const uint4*)hi;
    *(uint4*)(d + C) = *(const uint4*)lo;
}

// ============================================================================
// pre_all: fused preprocessing, ONE launch (round-7 proven).
// blocks [0,1024):    x row r -> LN stats + hi|lo split into Asplit.
// blocks [1024,5120): W1 row r -> row sum (fp64) into S1 + hi|lo split -> W1b.
// ============================================================================
__global__ void pre_all(const float* __restrict__ x, const float* __restrict__ W1,
                        float* __restrict__ mu, float* __restrict__ rstd,
                        float* __restrict__ S1,
                        unsigned short* __restrict__ Asplit,
                        unsigned short* __restrict__ W1b) {
    const int tid = threadIdx.x;
    const int lane = tid & 63, w = tid >> 6;
    const int c = tid * 8;
    __shared__ double shs[4], shq[4];
    if (blockIdx.x < 1024) {
        const int r = blockIdx.x;
        const float* p = x + (size_t)r * 2048 + c;
        float4 u0 = ((const float4*)p)[0];
        float4 u1 = ((const float4*)p)[1];
        float v[8] = {u0.x, u0.y, u0.z, u0.w, u1.x, u1.y, u1.z, u1.w};
        double s = 0.0, q = 0.0;
#pragma unroll
        for (int i = 0; i < 8; ++i) { s += v[i]; q += (double)v[i] * v[i]; }
        for (int o = 32; o > 0; o >>= 1) { s += __shfl_down(s, o, 64); q += __shfl_down(q, o, 64); }
        if (lane == 0) { shs[w] = s; shq[w] = q; }
        __syncthreads();
        if (tid == 0) {
            double S = shs[0] + shs[1] + shs[2] + shs[3];
            double Q = shq[0] + shq[1] + shq[2] + shq[3];
            double m = S / 2048.0;
            double var = Q / 2048.0 - m * m;
            mu[r] = (float)m;
            rstd[r] = (float)(1.0 / sqrt(var + 1e-5));
        }
        unsigned short hi[8], lo[8];
#pragma unroll
        for (int i = 0; i < 8; ++i) {
            hi[i] = f2b(v[i]);
            lo[i] = f2b(v[i] - b2f(hi[i]));
        }
        unsigned short* d = Asplit + (size_t)r * 4096 + c;
        *(uint4*)d = *(const uint4*)hi;
        *(uint4*)(d + 2048) = *(const uint4*)lo;
    } else {
        const int r = blockIdx.x - 1024;
        const float* p = W1 + (size_t)r * 2048 + c;
        float4 u0 = ((const float4*)p)[0];
        float4 u1 = ((const float4*)p)[1];
        float v[8] = {u0.x, u0.y, u0.z, u0.w, u1.x, u1.y, u1.z, u1.w};
        double s = 0.0;
#pragma unroll
        for (int i = 0; i < 8; ++i) s += v[i];
        for (int o = 32; o > 0; o >>= 1) s += __shfl_down(s, o, 64);
        if (lane == 0) shs[w] = s;
        __syncthreads();
        if (tid == 0) S1[r] = (float)(shs[0] + shs[1] + shs[2] + shs[3]);
        unsigned short hi[8], lo[8];
#pragma unroll
        for (int i = 0; i < 8; ++i) {
            hi[i] = f2b(v[i]);
            lo[i] = f2b(v[i] - b2f(hi[i]));
        }
        unsigned short* d = W1b + (size_t)r * 4096 + c;
        *(uint4*)d = *(const uint4*)hi;
        *(uint4*)(d + 2048) = *(const uint4*)lo;
    }
}

// flat f32 -> bf16, 8 el/thread
__global__ void cvt_kernel(const float* __restrict__ src,
                           unsigned short* __restrict__ dst) {
    const size_t i = ((size_t)blockIdx.x * 256 + threadIdx.x) * 8;
    float4 u0 = ((const float4*)(src + i))[0];
    float4 u1 = ((const float4*)(src + i))[1];
    float v[8] = {u0.x, u0.y, u0.z, u0.w, u1.x, u1.y, u1.z, u1.w};
    unsigned short t[8];
#pragma unroll
    for (int q = 0; q < 8; ++q) t[q] = f2b(v[q]);
    *(uint4*)(dst + i) = *(const uint4*)t;
}

// two-range flat f32 -> bf16 in one launch (W3 + Wout): kills one launch.
__global__ void cvt2_kernel(const float* __restrict__ s1, unsigned short* __restrict__ d1,
                            int nb1, const float* __restrict__ s2,
                            unsigned short* __restrict__ d2) {
    const int b = blockIdx.x;
    const float* src = (b < nb1) ? s1 : s2;
    unsigned short* dst = (b < nb1) ? d1 : d2;
    const int bb = (b < nb1) ? b : b - nb1;
    const size_t i = ((size_t)bb * 256 + threadIdx.x) * 8;
    float4 u0 = ((const float4*)(src + i))[0];
    float4 u1 = ((const float4*)(src + i))[1];
    float v[8] = {u0.x, u0.y, u0.z, u0.w, u1.x, u1.y, u1.z, u1.w};
    unsigned short t[8];
#pragma unroll
    for (int q = 0; q < 8; ++q) t[q] = f2b(v[q]);
    *(uint4*)(dst + i) = *(const uint4*)t;
}

// ============================================================================
// gemm_kan1: L1 FUSED hi/lo kernel, v3 = 8-WAVE (round-10 post-mortem).
// Evidence: time scales EXACTLY with per-wave MFMA count (r3 96x2065 vs
// r9/r10 64x3082 cyc, ratio 1.49=24/16) while staged bytes / ds_reads /
// barriers / conflicts all changed with zero effect -> latency-bound on the
// per-wave MFMA+dep stream at 2 waves/SIMD. Fix: 512 threads, 8 waves
// (2x4 grid, wave tile 32x32, acc[2][2], 12 MFMA/tile/wave) -> per-wave
// MFMA halves, waves/SIMD doubles (16/CU), same proven layout+schedule.
// Per K=32 tile: 3 MFMA groups hi*hi + lo*hi + hi*lo, operands staged ONCE.
// LDS: row r = [hi(32) | lo(32)] = 128-B rows, 8x16B slots, phys slot =
// logical ^ (row&7)  (round-10 measured: 0 conflicts). Staging source col
// for phys (r,u): v = u^(r&7); col = (v&3)*8 + (v>>2)*2048 + k0.
// Schedule: counted-vmcnt(3) triple-buffer 2-deep, 1 barrier/tile.
// Epilogue: lin = rstd*(acc - mu*S1) + bias, KAN+NCT, bf16 out.
// ============================================================================
__global__ __launch_bounds__(512, 4)
void gemm_kan1(const unsigned short* __restrict__ Ab,
               const unsigned short* __restrict__ Bb,
               const float* __restrict__ bias, const float* __restrict__ cp,
               const float* __restrict__ rw, const float* __restrict__ mu,
               const float* __restrict__ rstd, const float* __restrict__ S1,
               unsigned short* __restrict__ outp,
               int Nld, int Klog, int lda, int ldb)
{
    constexpr int BM = 64, BN = 128;
    constexpr int ABASE = 0, BBASE = 4096;   // shorts; A 64 rows, B 128 rows
    constexpr int BUF = 12288;               // 24 KB in shorts
    __shared__ unsigned short lds[3 * BUF];  // 72 KB triple buffer

    const int tid  = threadIdx.x;
    const int lane = tid & 63;
    const int wid  = tid >> 6;               // 0..7

    // XCD-chunked bijective swizzle (nwg = 512, %8==0)
    const int gx = gridDim.x;
    int flat = blockIdx.y * gx + blockIdx.x;
    const int nwg = gx * gridDim.y;
    if ((nwg & 7) == 0) flat = (flat & 7) * (nwg >> 3) + (flat >> 3);
    const int bm = (flat % gx) * BM;
    const int bn = (flat / gx) * BN;

    const int wmo = (wid >> 2) * 32;   // wave row offset within BM (2 rows)
    const int wno = (wid & 3) * 32;    // wave col offset within BN (4 cols)
    const int fr = lane & 15;
    const int kq = lane >> 4;
    const int sxr = fr & 7;            // read-side XOR term (row & 7)

    // staging unit u: LDS linear dest = u*16B (row u>>3, phys slot u&7);
    // logical slot v = (u&7)^(row&7); source col = (v&3)*8 + (v>>2)*2048.
    // A: 512 units (1/thread). B: 1024 units (2/thread).
    const int uA0 = tid;
    const int uB0 = tid, uB1 = tid + 512;
#define VLOG(u) ((((u) & 7)) ^ (((u) >> 3) & 7))
#define SRCC(u) (((VLOG(u) & 3) << 3) + ((VLOG(u) >> 2) * 2048))
    const size_t aoff0 = (size_t)(bm + (uA0 >> 3)) * lda + SRCC(uA0);
    const size_t boff0 = (size_t)(bn + (uB0 >> 3)) * ldb + SRCC(uB0);
    const size_t boff1 = (size_t)(bn + (uB1 >> 3)) * ldb + SRCC(uB1);
#undef SRCC
#undef VLOG

    f32x4 acc[2][2] = {};

#define STAGE(BSEL, K) do {                                           \
    unsigned short* l_ = &lds[(BSEL) * BUF];                          \
    gl16(l_ + ABASE + uA0 * 8, Ab + aoff0 + (K));                     \
    gl16(l_ + BBASE + uB0 * 8, Bb + boff0 + (K));                     \
    gl16(l_ + BBASE + uB1 * 8, Bb + boff1 + (K));                     \
} while (0)

    const int nt = Klog / 32;          // 64 tiles of logical K=32
    STAGE(0, 0);
    STAGE(1, 32);

    for (int t = 0; t < nt; ++t) {
        // counted drain: most recent STAGE (3 loads/thread) stays in flight
        // across the barrier; own t-tile loads (issued 2 iters ago) are done.
        if (t + 1 < nt) asm volatile("s_waitcnt vmcnt(3)" ::: "memory");
        else            asm volatile("s_waitcnt vmcnt(0)" ::: "memory");
        __builtin_amdgcn_s_barrier();
        __builtin_amdgcn_sched_barrier(0);  // pin ds_reads below the barrier
        if (t + 2 < nt) STAGE((t + 2) % 3, (t + 2) * 32);
        const unsigned short* cl = &lds[(t % 3) * BUF];
        const int slH = ((kq ^ sxr)) << 3;        // hi: logical slot kq
        const int slL = (((4 + kq) ^ sxr)) << 3;  // lo: logical slot 4+kq
        bf16x8 aH[2], aL[2], bH[2], bL[2];
#pragma unroll
        for (int i = 0; i < 2; ++i) {
            const int ro = ABASE + (wmo + i * 16 + fr) * 64;
            aH[i] = *(const bf16x8*)&cl[ro + slH];
            aL[i] = *(const bf16x8*)&cl[ro + slL];
        }
#pragma unroll
        for (int j = 0; j < 2; ++j) {
            const int ro = BBASE + (wno + j * 16 + fr) * 64;
            bH[j] = *(const bf16x8*)&cl[ro + slH];
            bL[j] = *(const bf16x8*)&cl[ro + slL];
        }
#pragma unroll
        for (int i = 0; i < 2; ++i)
#pragma unroll
            for (int j = 0; j < 2; ++j)
                acc[i][j] = __builtin_amdgcn_mfma_f32_16x16x32_bf16(aH[i], bH[j], acc[i][j], 0, 0, 0);
#pragma unroll
        for (int i = 0; i < 2; ++i)
#pragma unroll
            for (int j = 0; j < 2; ++j)
                acc[i][j] = __builtin_amdgcn_mfma_f32_16x16x32_bf16(aL[i], bH[j], acc[i][j], 0, 0, 0);
#pragma unroll
        for (int i = 0; i < 2; ++i)
#pragma unroll
            for (int j = 0; j < 2; ++j)
                acc[i][j] = __builtin_amdgcn_mfma_f32_16x16x32_bf16(aH[i], bL[j], acc[i][j], 0, 0, 0);
    }
#undef STAGE

    // ---- epilogue: C layout col = lane&15, row = (lane>>4)*4 + reg ----
    const int rowg = (lane >> 4) * 4;
#pragma unroll
    for (int j = 0; j < 2; ++j) {
        const int n = bn + wno + j * 16 + fr;
        const float bs = bias[n];
        float cpf[8];
#pragma unroll
        for (int q = 0; q < 8; ++q) cpf[q] = cp[(size_t)n * 9 + q];
        const float rwf = rw[n];
        const float s1 = S1[n];
        const int s = n & 7;  // generator slot: {0,1}->sx, {2,3}->sy, {4..7}->identity
#pragma unroll
        for (int i = 0; i < 2; ++i) {
            const int m0 = bm + wmo + i * 16 + rowg;
#pragma unroll
            for (int r = 0; r < 4; ++r) {
                const int m = m0 + r;
                float v = acc[i][j][r];
                v = (v - mu[m] * s1) * rstd[m] + bs;
                v = kan_spline(tanhf(v), cpf, rwf);
                float p = __shfl_xor(v, 1, 64);  // partner col n^1 lives in lane^1
                p = fminf(fmaxf(p, -1.0f), 1.0f);
                if (s < 4) v += ((s == 2) ? -0.05f : 0.05f) * p;
                outp[(size_t)m * Nld + n] = f2b(v);
            }
        }
    }
}

// ============================================================================
// gemm_kan2: ROUND-3 EXACT core (measured 79.5 us, reproduced 4x).
// C[1024 x Ncols] = A @ B^T, bf16 inputs, fused LN-fold/KAN/NCT.
// BM=64 BN=128 BK=64, 4 waves 2x2 (wave tile 32x64, acc[2][4]); 512-block
// grids = 2 blocks/CU where possible. Triple-buffered LDS (72 KB), 2-deep
// global_load_lds prefetch, ONE raw s_barrier per K-step preceded by COUNTED
// s_waitcnt vmcnt(6). sched_barrier pins ds_reads below the barrier. XOR
// bank-conflict swizzle source+read side, LDS dest linear (0 conflicts).
// XCD-chunked grid swizzle.
// EPI 0: lin = rstd*(acc - mu*S1) + bias, KAN+NCT, bf16 out (Ktot=6144
//        mapped: seg0 hi*hi, seg1 lo*hi, seg2 hi*lo — HALF path only).
// EPI 1: acc+bias, KAN+NCT, bf16.  EPI 2: acc+bias, f32.
// ============================================================================
template <int EPI>
__global__ __launch_bounds__(256, 2)
void gemm_kan2(const unsigned short* __restrict__ Ab,
               const unsigned short* __restrict__ Bb,
               const float* __restrict__ bias, const float* __restrict__ cp,
               const float* __restrict__ rw, const float* __restrict__ mu,
               const float* __restrict__ rstd, const float* __restrict__ S1,
               void* __restrict__ outp,
               int Nld, int n0, int Ktot, int lda, int ldb)
{
    constexpr int BM = 64, BN = 128, BK = 64;
    constexpr int ASZ = BM * BK;        // 4096 shorts = 8 KB
    constexpr int BUF = ASZ + BN * BK;  // 12288 shorts = 24 KB
    __shared__ unsigned short lds[3 * BUF];  // 72 KB triple buffer

    const int tid  = threadIdx.x;
    const int lane = tid & 63;
    const int wid  = tid >> 6;

    // XCD-chunked bijective swizzle (nwg % 8 == 0 for every launch here)
    const int gx = gridDim.x;
    int flat = blockIdx.y * gx + blockIdx.x;
    const int nwg = gx * gridDim.y;
    if ((nwg & 7) == 0) flat = (flat & 7) * (nwg >> 3) + (flat >> 3);
    const int bm = (flat % gx) * BM;
    const int bn = (flat / gx) * BN;

    const int wmo = (wid >> 1) * 32;   // wave row offset within BM
    const int wno = (wid & 1) * 64;    // wave col offset within BN
    const int fr = lane & 15;
    const int kq = lane >> 4;
    const int sxr = fr & 7;            // read-side XOR term (row & 7)

    // staging unit u: LDS linear dest = u*16B (row u>>3, 16B-slot u&7);
    // global source slot = (u&7) ^ (row&7)   [inverse swizzle on source]
    const int uA0 = (wid << 7) + lane;          // A: 512 units, 2 per thread
    const int uA1 = uA0 + 64;
    const int uB0 = (wid << 8) + lane;          // B: 1024 units, 4 per thread
    const int uB1 = uB0 + 64, uB2 = uB0 + 128, uB3 = uB0 + 192;
#define SRCOL(u) (((((u) & 7) ^ (((u) >> 3) & 7))) << 3)
    const size_t aoff0 = (size_t)(bm + (uA0 >> 3)) * lda + SRCOL(uA0);
    const size_t aoff1 = (size_t)(bm + (uA1 >> 3)) * lda + SRCOL(uA1);
    const size_t boff0 = (size_t)(bn + (uB0 >> 3)) * ldb + SRCOL(uB0);
    const size_t boff1 = (size_t)(bn + (uB1 >> 3)) * ldb + SRCOL(uB1);
    const size_t boff2 = (size_t)(bn + (uB2 >> 3)) * ldb + SRCOL(uB2);
    const size_t boff3 = (size_t)(bn + (uB3 >> 3)) * ldb + SRCOL(uB3);
#undef SRCOL

    f32x4 acc[2][4] = {};

#define STAGE(BSEL, AK, BKK) do {                                     \
    unsigned short* lA_ = &lds[(BSEL) * BUF];                         \
    unsigned short* lB_ = lA_ + ASZ;                                  \
    gl16(lA_ + uA0 * 8, Ab + aoff0 + (AK));                           \
    gl16(lA_ + uA1 * 8, Ab + aoff1 + (AK));                           \
    gl16(lB_ + uB0 * 8, Bb + boff0 + (BKK));                          \
    gl16(lB_ + uB1 * 8, Bb + boff1 + (BKK));                          \
    gl16(lB_ + uB2 * 8, Bb + boff2 + (BKK));                          \
    gl16(lB_ + uB3 * 8, Bb + boff3 + (BKK));                          \
} while (0)

    const int nt = Ktot / BK;
    STAGE(0, 0, 0);
    STAGE(1, BK, BK);   // kn=64 < 2048: no segment remap needed at any EPI

    for (int t = 0; t < nt; ++t) {
        // counted drain: allow the (t+1)-tile STAGE (6 loads) to stay in
        // flight across the barrier; own t-tile loads are then complete.
        if (t + 1 < nt) asm volatile("s_waitcnt vmcnt(6)" ::: "memory");
        else            asm volatile("s_waitcnt vmcnt(0)" ::: "memory");
        __builtin_amdgcn_s_barrier();
        __builtin_amdgcn_sched_barrier(0);  // pin ds_reads below the barrier
        if (t + 2 < nt) {
            const int kn = (t + 2) * BK;
            int ak = kn, bk = kn;
            if (EPI == 0) {
                ak = (kn < 4096) ? kn : kn - 4096;
                bk = (kn < 2048) ? kn : kn - 2048;
            }
            STAGE((t + 2) % 3, ak, bk);
        }
        const unsigned short* cl = &lds[(t % 3) * BUF];
#pragma unroll
        for (int s = 0; s < 2; ++s) {
            const int sl = ((((s << 2) + kq) ^ sxr)) << 3;  // swizzled 16B slot
            bf16x8 aF[2], bF[4];
#pragma unroll
            for (int i = 0; i < 2; ++i)
                aF[i] = *(const bf16x8*)&cl[(wmo + i * 16 + fr) * BK + sl];
#pragma unroll
            for (int j = 0; j < 4; ++j)
                bF[j] = *(const bf16x8*)&cl[ASZ + (wno + j * 16 + fr) * BK + sl];
#pragma unroll
            for (int i = 0; i < 2; ++i)
#pragma unroll
                for (int j = 0; j < 4; ++j)
                    acc[i][j] = __builtin_amdgcn_mfma_f32_16x16x32_bf16(aF[i], bF[j], acc[i][j], 0, 0, 0);
        }
    }
#undef STAGE

    // ---- epilogue: C layout col = lane&15, row = (lane>>4)*4 + reg ----
    const int rowg = (lane >> 4) * 4;
#pragma unroll
    for (int j = 0; j < 4; ++j) {
        const int n = n0 + bn + wno + j * 16 + fr;
        const float bs = bias[n];
        float cpf[8], rwf = 0.0f, s1 = 0.0f;
        if (EPI < 2) {
#pragma unroll
            for (int q = 0; q < 8; ++q) cpf[q] = cp[(size_t)n * 9 + q];
            rwf = rw[n];
        }
        if (EPI == 0) s1 = S1[n];
        const int s = n & 7;  // generator slot: {0,1}->sx, {2,3}->sy, {4..7}->identity
#pragma unroll
        for (int i = 0; i < 2; ++i) {
            const int m0 = bm + wmo + i * 16 + rowg;
#pragma unroll
            for (int r = 0; r < 4; ++r) {
                const int m = m0 + r;
                float v = acc[i][j][r];
                if (EPI == 0) v = (v - mu[m] * s1) * rstd[m] + bs;
                else          v += bs;
                if (EPI < 2) {
                    v = kan_spline(tanhf(v), cpf, rwf);
                    float p = __shfl_xor(v, 1, 64);  // partner col n^1 lives in lane^1
                    p = fminf(fmaxf(p, -1.0f), 1.0f);
                    if (s < 4) v += ((s == 2) ? -0.05f : 0.05f) * p;
                }
                if (EPI == 2) ((float*)outp)[(size_t)m * Nld + n] = v;
                else ((unsigned short*)outp)[(size_t)m * Nld + n] = f2b(v);
            }
        }
    }
}

// ============================================================================
// Legacy 64x64 kernel kept ONLY for the small-workspace insurance path
// (in-loop f32->bf16 conversion variants BSRC 1/2). Unchanged.
// ============================================================================
template <int EPI, int BSRC>
__global__ __launch_bounds__(256, 2)
void gemm_kan(const void* __restrict__ Av, const void* __restrict__ Bv,
              const float* __restrict__ bias, const float* __restrict__ cp,
              const float* __restrict__ rw, const float* __restrict__ mu,
              const float* __restrict__ rstd, const float* __restrict__ S1,
              void* __restrict__ outp,
              int Nld, int n0, int Ktot, int lda, int ldb)
{
    constexpr int BM = 64, BN = 64, BK = 64, LDP = 72;
    constexpr bool SPL = (BSRC == 2);
    constexpr int OFF_B  = BM * LDP;
    constexpr int OFF_LO = (BM + BN) * LDP;
    __shared__ unsigned short lds[(SPL ? 2 : 1) * (BM + BN) * LDP];

    const int tid  = threadIdx.x;
    const int lane = tid & 63;
    const int wid  = tid >> 6;
    const int bm = blockIdx.x * BM;
    const int bn = blockIdx.y * BN;
    const int wmo = (wid >> 1) * 32;
    const int wno = (wid & 1) * 32;
    const int fr = lane & 15;
    const int kq = lane >> 4;
    const int sar = tid >> 3, sac = (tid & 7) << 3;
    const int sfr = tid >> 2, sfc = (tid & 3) << 4;

    f32x4 acc[2][2] = {};

    uint4 pA0 = {}, pA1 = {}, pB0 = {}, pB1 = {};
    const unsigned short* Ab = (const unsigned short*)Av;
    const unsigned short* Bb = (const unsigned short*)Bv;
    const size_t a0 = (size_t)(bm + sar) * lda + sac;
    const size_t a1 = (size_t)(bm + 32 + sar) * lda + sac;
    const size_t b0 = (size_t)(bn + sar) * ldb + sac;
    const size_t b1 = (size_t)(bn + 32 + sar) * ldb + sac;
    if constexpr (BSRC == 0) {
        pA0 = *(const uint4*)(Ab + a0);
        pA1 = *(const uint4*)(Ab + a1);
        pB0 = *(const uint4*)(Bb + b0);
        pB1 = *(const uint4*)(Bb + b1);
    }

    for (int k0 = 0; k0 < Ktot; k0 += BK) {
        if constexpr (BSRC == 0) {
            *(uint4*)&lds[sar * LDP + sac] = pA0;
            *(uint4*)&lds[(32 + sar) * LDP + sac] = pA1;
            *(uint4*)&lds[OFF_B + sar * LDP + sac] = pB0;
            *(uint4*)&lds[OFF_B + (32 + sar) * LDP + sac] = pB1;
        } else {
            {
                const float* g = (const float*)Bv + (size_t)(bn + sfr) * ldb + k0 + sfc;
                float4 u0 = ((const float4*)g)[0];
                float4 u1 = ((const float4*)g)[1];
                float4 u2 = ((const float4*)g)[2];
                float4 u3 = ((const float4*)g)[3];
                float v[16] = {u0.x,u0.y,u0.z,u0.w, u1.x,u1.y,u1.z,u1.w,
                               u2.x,u2.y,u2.z,u2.w, u3.x,u3.y,u3.z,u3.w};
                unsigned short hi[16], lo[16];
#pragma unroll
                for (int i = 0; i < 16; ++i) {
                    hi[i] = f2b(v[i]);
                    if (SPL) lo[i] = f2b(v[i] - b2f(hi[i]));
                }
                unsigned short* d = &lds[OFF_B + sfr * LDP + sfc];
                ((uint4*)d)[0] = *(const uint4*)&hi[0];
                ((uint4*)d)[1] = *(const uint4*)&hi[8];
                if constexpr (SPL) {
                    unsigned short* dl = d + OFF_LO;
                    ((uint4*)dl)[0] = *(const uint4*)&lo[0];
                    ((uint4*)dl)[1] = *(const uint4*)&lo[8];
                }
            }
            if constexpr (SPL) {
                const float* g = (const float*)Av + (size_t)(bm + sfr) * lda + k0 + sfc;
                float4 u0 = ((const float4*)g)[0];
                float4 u1 = ((const float4*)g)[1];
                float4 u2 = ((const float4*)g)[2];
                float4 u3 = ((const float4*)g)[3];
                float v[16] = {u0.x,u0.y,u0.z,u0.w, u1.x,u1.y,u1.z,u1.w,
                               u2.x,u2.y,u2.z,u2.w, u3.x,u3.y,u3.z,u3.w};
                unsigned short hi[16], lo[16];
#pragma unroll
                for (int i = 0; i < 16; ++i) {
                    hi[i] = f2b(v[i]);
                    lo[i] = f2b(v[i] - b2f(hi[i]));
                }
                unsigned short* d = &lds[sfr * LDP + sfc];
                ((uint4*)d)[0] = *(const uint4*)&hi[0];
                ((uint4*)d)[1] = *(const uint4*)&hi[8];
                unsigned short* dl = d + OFF_LO;
                ((uint4*)dl)[0] = *(const uint4*)&lo[0];
                ((uint4*)dl)[1] = *(const uint4*)&lo[8];
            } else {
                *(uint4*)&lds[sar * LDP + sac] = *(const uint4*)(Ab + a0 + k0);
                *(uint4*)&lds[(32 + sar) * LDP + sac] = *(const uint4*)(Ab + a1 + k0);
            }
        }
        __syncthreads();
        if constexpr (BSRC == 0) {
            if (k0 + BK < Ktot) {
                const int kn = k0 + BK;
                const int ak = (EPI == 0) ? (kn < 4096 ? kn : kn - 4096) : kn;
                const int bk = (EPI == 0) ? (kn < 2048 ? kn : kn - 2048) : kn;
                pA0 = *(const uint4*)(Ab + a0 + ak);
                pA1 = *(const uint4*)(Ab + a1 + ak);
                pB0 = *(const uint4*)(Bb + b0 + bk);
                pB1 = *(const uint4*)(Bb + b1 + bk);
            }
        }
#pragma unroll
        for (int s = 0; s < 2; ++s) {
            const int cc = (s * 4 + kq) << 3;
            bf16x8 aF[2], bF[2];
#pragma unroll
            for (int i = 0; i < 2; ++i)
                aF[i] = *(const bf16x8*)&lds[(wmo + i * 16 + fr) * LDP + cc];
#pragma unroll
            for (int j = 0; j < 2; ++j)
                bF[j] = *(const bf16x8*)&lds[OFF_B + (wno + j * 16 + fr) * LDP + cc];
#pragma unroll
            for (int i = 0; i < 2; ++i)
#pragma unroll
                for (int j = 0; j < 2; ++j)
                    acc[i][j] = __builtin_amdgcn_mfma_f32_16x16x32_bf16(aF[i], bF[j], acc[i][j], 0, 0, 0);
            if constexpr (SPL) {
                bf16x8 aL[2], bL[2];
#pragma unroll
                for (int i = 0; i < 2; ++i)
                    aL[i] = *(const bf16x8*)&lds[OFF_LO + (wmo + i * 16 + fr) * LDP + cc];
#pragma unroll
                for (int i = 0; i < 2; ++i)
#pragma unroll
                    for (int j = 0; j < 2; ++j)
                        acc[i][j] = __builtin_amdgcn_mfma_f32_16x16x32_bf16(aL[i], bF[j], acc[i][j], 0, 0, 0);
#pragma unroll
                for (int j = 0; j < 2; ++j)
                    bL[j] = *(const bf16x8*)&lds[OFF_LO + OFF_B + (wno + j * 16 + fr) * LDP + cc];
#pragma unroll
                for (int i = 0; i < 2; ++i)
#pragma unroll
                    for (int j = 0; j < 2; ++j)
                        acc[i][j] = __builtin_amdgcn_mfma_f32_16x16x32_bf16(aF[i], bL[j], acc[i][j], 0, 0, 0);
            }
        }
        __syncthreads();
    }

    const int rowg = (lane >> 4) * 4;
#pragma unroll
    for (int j = 0; j < 2; ++j) {
        const int n = n0 + bn + wno + j * 16 + fr;
        const float bs = bias[n];
        float cpf[8], rwf = 0.0f, s1 = 0.0f;
        if (EPI < 2) {
#pragma unroll
            for (int q = 0; q < 8; ++q) cpf[q] = cp[(size_t)n * 9 + q];
            rwf = rw[n];
        }
        if (EPI == 0) s1 = S1[n];
        const int s = n & 7;
#pragma unroll
        for (int i = 0; i < 2; ++i) {
            const int m0 = bm + wmo + i * 16 + rowg;
#pragma unroll
            for (int r = 0; r < 4; ++r) {
                const int m = m0 + r;
                float v = acc[i][j][r];
                if (EPI == 0) v = (v - mu[m] * s1) * rstd[m] + bs;
                else          v += bs;
                if (EPI < 2) {
                    v = kan_spline(tanhf(v), cpf, rwf);
                    float p = __shfl_xor(v, 1, 64);
                    p = fminf(fmaxf(p, -1.0f), 1.0f);
                    if (s < 4) v += ((s == 2) ? -0.05f : 0.05f) * p;
                }
                if (EPI == 2) ((float*)outp)[(size_t)m * Nld + n] = v;
                else ((unsigned short*)outp)[(size_t)m * Nld + n] = f2b(v);
            }
        }
    }
}

extern "C" void kernel_launch(void* const* d_in, const int* in_sizes, int n_in,
                              void* d_out, int out_size, void* d_ws, size_t ws_size,
                              hipStream_t stream) {
    const float* x    = (const float*)d_in[0];
    const float* W1   = (const float*)d_in[1];
    const float* b1   = (const float*)d_in[2];
    const float* cp1  = (const float*)d_in[3];
    const float* rw1  = (const float*)d_in[4];
    const float* W2   = (const float*)d_in[5];
    const float* b2   = (const float*)d_in[6];
    const float* cp2  = (const float*)d_in[7];
    const float* rw2  = (const float*)d_in[8];
    const float* W3   = (const float*)d_in[9];
    const float* b3   = (const float*)d_in[10];
    const float* cp3  = (const float*)d_in[11];
    const float* rw3  = (const float*)d_in[12];
    const float* Wout = (const float*)d_in[13];
    const float* bout = (const float*)d_in[14];

    char* ws = (char*)d_ws;
    float* mu   = (float*)(ws);                  // 1024 f32
    float* rstd = (float*)(ws + 4096);           // 1024 f32
    float* S1   = (float*)(ws + 8192);           // 4096 f32
    unsigned short* A2 = (unsigned short*)(ws + 32768);              // 1024x4096 bf16 (8MB)
    unsigned short* A3 = (unsigned short*)(ws + 32768 + 8388608);    // 1024x4096 bf16 (8MB)
    unsigned short* A4 = A2;                      // A2 dead after L2 gemm
    unsigned short* Asplit = A3;                  // x split lives in A3 slot until L2 writes it
    unsigned short* Wb = (unsigned short*)(ws + 32768 + 2 * 8388608); // 32MB region
    const size_t NEED_FULL = 32768 + 2 * 8388608 + 33554432;  // 50.4 MB
    const size_t NEED_HALF = 32768 + 2 * 8388608 + 16777216;  // 33.6 MB

    if (ws_size >= NEED_FULL) {
        // 7 launches (round-7 structure; L1 uses the 8-wave fused hi/lo v3).
        pre_all<<<5120, 256, 0, stream>>>(x, W1, mu, rstd, S1, Asplit, Wb);
        gemm_kan1<<<dim3(16, 32), 512, 0, stream>>>(
            Asplit, Wb, b1, cp1, rw1, mu, rstd, S1, A2, 4096, 2048, 4096, 4096);
        cvt_kernel<<<8192, 256, 0, stream>>>(W2, Wb);
        gemm_kan2<1><<<dim3(16, 32), 256, 0, stream>>>(
            A2, Wb, b2, cp2, rw2, nullptr, nullptr, nullptr, A3, 4096, 0, 4096, 4096, 4096);
        cvt2_kernel<<<6144, 256, 0, stream>>>(W3, Wb, 4096, Wout, Wb + 8388608);
        gemm_kan2<1><<<dim3(16, 16), 256, 0, stream>>>(
            A3, Wb, b3, cp3, rw3, nullptr, nullptr, nullptr, A4, 2048, 0, 4096, 4096, 4096);
        gemm_kan2<2><<<dim3(16, 16), 256, 0, stream>>>(
            A4, Wb + 8388608, bout, nullptr, nullptr, nullptr, nullptr, nullptr, d_out, 2048, 0, 2048, 2048, 2048);
    } else if (ws_size >= NEED_HALF) {
        ln_stats_kernel<<<1024, 256, 0, stream>>>(x, mu, rstd);
        rowsum_kernel<<<1024, 256, 0, stream>>>(W1, S1, 2048);
        split2_kernel<<<1024, 256, 0, stream>>>(x, Asplit, 2048);
        for (int h = 0; h < 2; ++h) {
            split2_kernel<<<2048, 256, 0, stream>>>(W1 + (size_t)h * 2048 * 2048, Wb, 2048);
            gemm_kan2<0><<<dim3(16, 16), 256, 0, stream>>>(
                Asplit, Wb, b1, cp1, rw1, mu, rstd, S1, A2, 4096, h * 2048, 6144, 4096, 4096);
        }
        for (int h = 0; h < 2; ++h) {
            cvt_kernel<<<4096, 256, 0, stream>>>(W2 + (size_t)h * 2048 * 4096, Wb);
            gemm_kan2<1><<<dim3(16, 16), 256, 0, stream>>>(
                A2, Wb, b2, cp2, rw2, nullptr, nullptr, nullptr, A3, 4096, h * 2048, 4096, 4096, 4096);
        }
        cvt_kernel<<<4096, 256, 0, stream>>>(W3, Wb);
        gemm_kan2<1><<<dim3(16, 16), 256, 0, stream>>>(
            A3, Wb, b3, cp3, rw3, nullptr, nullptr, nullptr, A4, 2048, 0, 4096, 4096, 4096);
        cvt_kernel<<<2048, 256, 0, stream>>>(Wout, Wb);
        gemm_kan2<2><<<dim3(16, 16), 256, 0, stream>>>(
            A4, Wb, bout, nullptr, nullptr, nullptr, nullptr, nullptr, d_out, 2048, 0, 2048, 2048, 2048);
    } else {
        // 16.8 MB insurance path: in-loop conversion (round-4-proven staging)
        ln_stats_kernel<<<1024, 256, 0, stream>>>(x, mu, rstd);
        rowsum_kernel<<<1024, 256, 0, stream>>>(W1, S1, 2048);
        gemm_kan<0, 2><<<dim3(16, 64), 256, 0, stream>>>(
            x, W1, b1, cp1, rw1, mu, rstd, S1, A2, 4096, 0, 2048, 2048, 2048);
        gemm_kan<1, 1><<<dim3(16, 64), 256, 0, stream>>>(
            A2, W2, b2, cp2, rw2, nullptr, nullptr, nullptr, A3, 4096, 0, 4096, 4096, 4096);
        gemm_kan<1, 1><<<dim3(16, 32), 256, 0, stream>>>(
            A3, W3, b3, cp3, rw3, nullptr, nullptr, nullptr, A4, 2048, 0, 4096, 4096, 4096);
        gemm_kan<2, 1><<<dim3(16, 32), 256, 0, stream>>>(
            A4, Wout, bout, nullptr, nullptr, nullptr, nullptr, nullptr, d_out, 2048, 0, 2048, 2048, 2048);
    }
}